// Round 1
// 77.823 us; speedup vs baseline: 1.0025x; 1.0025x over previous
//
#include <hip/hip_runtime.h>

// Problem constants (from reference)
#define BB  8
#define PP  16
#define LL  256     // events per path
#define MM  16      // models
#define LE  2048    // query times per path
#define THREADS 512
#define TILE THREADS   // one query per thread

// Branch-free compare-accumulate over one float4 of events:
// cin += #elems < q ; tl = max(tl, max elem < q)
__device__ __forceinline__ void acc4(const float4 v, const float q, int& cin, float& tl)
{
    bool c;
    c = (v.x < q); cin += c; tl = c ? fmaxf(tl, v.x) : tl;
    c = (v.y < q); cin += c; tl = c ? fmaxf(tl, v.y) : tl;
    c = (v.z < q); cin += c; tl = c ? fmaxf(tl, v.z) : tl;
    c = (v.w < q); cin += c; tl = c ? fmaxf(tl, v.w) : tl;
}

// Grid: (B*P) * (LE/TILE) = 512 blocks. Each block owns one (b,p) pair and a
// tile of 512 queries (one per thread). All M=16 models' params for this (b,p)
// staged in LDS (48 KB packed), 2 blocks/CU -> 16 waves/CU (4/SIMD).
__global__ __launch_bounds__(THREADS, 4) void hawkes_intensity_kernel(
    const float* __restrict__ qt,     // [B,P,LE]
    const float* __restrict__ ev,     // [B,P,LL] sorted ascending
    const float* __restrict__ mu,     // [B,M,P,LL]
    const float* __restrict__ alpha,  // [B,M,P,LL]
    const float* __restrict__ beta,   // [B,M,P,LL]
    float* __restrict__ out)          // [B,M,P,LE]
{
    __shared__ float2 pma_s[MM * LL];           // (mu, alpha-mu)  32 KB
    __shared__ float  pnb_s[MM * LL];           // -beta           16 KB
    __shared__ __align__(16) float ev_s[LL];    // events           1 KB

    const int tiles_per_bp = LE / TILE;         // 4
    const int bp   = blockIdx.x / tiles_per_bp; // 0..127
    const int tile = blockIdx.x % tiles_per_bp;
    const int b = bp / PP;
    const int p = bp % PP;
    const int t = threadIdx.x;

    const int le = tile * TILE + t;
    const float q = qt[bp * LE + le];           // global load, issues before LDS wait

    // ---- stage events (256 floats; first 256 threads) ----
    if (t < LL) ev_s[t] = ev[bp * LL + t];

    // ---- stage params: 3 x 4096 floats, coalesced b32 loads, precompute
    //      (alpha-mu) and (-beta) once here instead of per-query. ----
    #pragma unroll
    for (int i = t; i < MM * LL; i += THREADS) {   // 8 iterations
        const int m = i >> 8;                      // / LL
        const int l = i & (LL - 1);
        const int g = ((b * MM + m) * PP + p) * LL + l;
        const float mm = mu[g];
        const float aa = alpha[g];
        const float bb = beta[g];
        pma_s[i] = make_float2(mm, aa - mm);
        pnb_s[i] = -bb;
    }
    __syncthreads();

    // ---- count events strictly < q, two-level, branch-free ----
    // Level 1: 16 chunk pivots ev_s[16j+15] (max of chunk j, sorted input).
    // Same address across all lanes -> LDS broadcast, no conflicts, no chain.
    int F = 0;          // number of fully-past 16-event chunks
    float tl = 0.0f;    // running max event < q (0 if none -> matches reference)
    #pragma unroll
    for (int j = 0; j < 16; ++j) {
        const float r = ev_s[j * 16 + 15];
        const bool c = (r < q);
        F += c;
        tl = c ? fmaxf(tl, r) : tl;
    }
    const int Fc = (F < 16) ? F : 15;

    // Level 2: one 16-element chunk via 4 INDEPENDENT ds_read_b128 (single
    // latency round-trip instead of 9 dependent reads).
    const float4* ev4 = (const float4*)ev_s;
    const float4 w0 = ev4[Fc * 4 + 0];
    const float4 w1 = ev4[Fc * 4 + 1];
    const float4 w2 = ev4[Fc * 4 + 2];
    const float4 w3 = ev4[Fc * 4 + 3];
    int cin = 0;
    acc4(w0, q, cin, tl);
    acc4(w1, q, cin, tl);
    acc4(w2, q, cin, tl);
    acc4(w3, q, cin, tl);

    // F==16 case folds in automatically: Fc=15, cin=16 -> cnt=256.
    const int cnt = Fc * 16 + cin;              // #events < q
    const int ci  = (cnt > 0) ? (cnt - 1) : 0;  // clamp like reference
    const float dt = q - tl;                    // tl==0 when cnt==0

    // ---- M-loop: 16 outputs, fully unrolled, independent iterations ----
    int o = (b * MM * PP + p) * LE + le;        // (b, m=0, p, le)
    #pragma unroll
    for (int m = 0; m < MM; ++m) {
        const float2 pm = pma_s[(m << 8) | ci]; // b64: (mu, alpha-mu)
        const float  nb = pnb_s[(m << 8) | ci]; // b32: -beta
        const float  e  = __expf(nb * dt);
        const float  base = fmaf(pm.y, e, pm.x);     // in [0,1)
        out[o] = __logf(1.0f + __expf(base));        // softplus, safe range
        o += PP * LE;                                // next m
    }
}

extern "C" void kernel_launch(void* const* d_in, const int* in_sizes, int n_in,
                              void* d_out, int out_size, void* d_ws, size_t ws_size,
                              hipStream_t stream) {
    const float* qt    = (const float*)d_in[0];  // query_times [B,P,LE]
    const float* ev    = (const float*)d_in[1];  // event_times [B,P,LL]
    const float* mu    = (const float*)d_in[2];  // [B,M,P,LL]
    const float* alpha = (const float*)d_in[3];
    const float* beta  = (const float*)d_in[4];
    float* out = (float*)d_out;                  // [B,M,P,LE] fp32

    const int nblocks = (BB * PP) * (LE / TILE); // 512
    hawkes_intensity_kernel<<<nblocks, THREADS, 0, stream>>>(qt, ev, mu, alpha, beta, out);
}